// Round 1
// baseline (5886.689 us; speedup 1.0000x reference)
//
#include <hip/hip_runtime.h>

// VGAE forward, MI355X. All fp32.
// Sizes fixed by the reference problem.
constexpr int N_ = 50000;
constexpr int E_ = 1600000;
constexpr int D_ = 128;   // embedding_dim == hidden_dim
constexpr int O_ = 64;    // out_embedding_dim
constexpr int NNZ_ = 16;

// ---------------------------------------------------------------------------
// 1. EmbeddingBag(sum, per_sample_weights) + L2 normalize. One wave per node.
// ---------------------------------------------------------------------------
__global__ __launch_bounds__(256) void k_embed(const int* __restrict__ fi,
                                               const float* __restrict__ fw,
                                               const float* __restrict__ emb,
                                               float* __restrict__ x) {
    int n = blockIdx.x * 4 + (threadIdx.x >> 6);
    if (n >= N_) return;
    int lane = threadIdx.x & 63;
    float a0 = 0.f, a1 = 0.f;
    int base = n * NNZ_;
#pragma unroll
    for (int j = 0; j < NNZ_; ++j) {
        int idx  = fi[base + j];
        float w  = fw[base + j];
        const float* r = emb + (size_t)idx * D_;
        a0 = fmaf(w, r[lane], a0);
        a1 = fmaf(w, r[lane + 64], a1);
    }
    float ss = a0 * a0 + a1 * a1;
#pragma unroll
    for (int o = 32; o; o >>= 1) ss += __shfl_xor(ss, o);
    float sc = 1.0f / fmaxf(sqrtf(ss), 1e-12f);
    x[(size_t)n * D_ + lane]      = a0 * sc;
    x[(size_t)n * D_ + lane + 64] = a1 * sc;
}

// ---------------------------------------------------------------------------
// 2. Degree count (in-degree of dst) + normalization factors
// ---------------------------------------------------------------------------
__global__ __launch_bounds__(256) void k_degcnt(const int* __restrict__ dst,
                                                float* __restrict__ cnt) {
    int e = blockIdx.x * blockDim.x + threadIdx.x;
    if (e < E_) atomicAdd(&cnt[dst[e]], 1.0f);
}

__global__ __launch_bounds__(256) void k_degnorm(const float* __restrict__ cnt,
                                                 float* __restrict__ disq,
                                                 float* __restrict__ dinv) {
    int n = blockIdx.x * blockDim.x + threadIdx.x;
    if (n < N_) {
        float deg = 1.0f + cnt[n];
        disq[n] = rsqrtf(deg);
        dinv[n] = 1.0f / deg;
    }
}

// ---------------------------------------------------------------------------
// 3. agg init with self-loop term: agg[n] = deg_inv[n] * v[n]   (D=128)
// ---------------------------------------------------------------------------
__global__ __launch_bounds__(256) void k_initagg(const float* __restrict__ v,
                                                 const float* __restrict__ dinv,
                                                 float* __restrict__ agg) {
    int t = blockIdx.x * blockDim.x + threadIdx.x;   // over N*32 float4
    if (t < N_ * (D_ / 4)) {
        int n = t >> 5;
        float4 a = ((const float4*)v)[t];
        float s = dinv[n];
        a.x *= s; a.y *= s; a.z *= s; a.w *= s;
        ((float4*)agg)[t] = a;
    }
}

// ---------------------------------------------------------------------------
// 4. Edge scatter: agg[dst] += disq[src]*disq[dst] * v[src]   (D=128)
//    32 lanes per edge, float4 per lane, 4 f32 atomics per lane.
// ---------------------------------------------------------------------------
__global__ __launch_bounds__(256) void k_scatter(const int* __restrict__ src,
                                                 const int* __restrict__ dst,
                                                 const float* __restrict__ disq,
                                                 const float* __restrict__ v,
                                                 float* __restrict__ agg) {
    int e = blockIdx.x * 8 + (threadIdx.x >> 5);
    if (e >= E_) return;
    int l = threadIdx.x & 31;
    int s = src[e], d = dst[e];
    float ne = disq[s] * disq[d];
    float4 a = ((const float4*)(v + (size_t)s * D_))[l];
    float* o = agg + (size_t)d * D_ + l * 4;
    atomicAdd(o + 0, ne * a.x);
    atomicAdd(o + 1, ne * a.y);
    atomicAdd(o + 2, ne * a.z);
    atomicAdd(o + 3, ne * a.w);
}

// ---------------------------------------------------------------------------
// 5. h = relu(u @ W1 + b1), W1 [128x128] staged in LDS. 8 rows per block-pass.
// ---------------------------------------------------------------------------
__global__ __launch_bounds__(256) void k_gemm_relu(const float* __restrict__ u,
                                                   const float* __restrict__ W,
                                                   const float* __restrict__ b,
                                                   float* __restrict__ h) {
    __shared__ float lw[D_ * D_];            // 64 KiB
    for (int t = threadIdx.x; t < D_ * D_ / 4; t += 256)
        ((float4*)lw)[t] = ((const float4*)W)[t];
    __syncthreads();
    int sub = threadIdx.x >> 5, l = threadIdx.x & 31;
    float4 bb = ((const float4*)b)[l];
    for (int row = blockIdx.x * 8 + sub; row < N_; row += gridDim.x * 8) {
        const float* ur = u + (size_t)row * D_;
        float4 acc = {0.f, 0.f, 0.f, 0.f};
#pragma unroll 4
        for (int k = 0; k < D_; ++k) {
            float uv = ur[k];
            float4 w = ((const float4*)lw)[k * 32 + l];
            acc.x = fmaf(uv, w.x, acc.x);
            acc.y = fmaf(uv, w.y, acc.y);
            acc.z = fmaf(uv, w.z, acc.z);
            acc.w = fmaf(uv, w.w, acc.w);
        }
        acc.x = fmaxf(acc.x + bb.x, 0.f);
        acc.y = fmaxf(acc.y + bb.y, 0.f);
        acc.z = fmaxf(acc.z + bb.z, 0.f);
        acc.w = fmaxf(acc.w + bb.w, 0.f);
        ((float4*)(h + (size_t)row * D_))[l] = acc;
    }
}

// ---------------------------------------------------------------------------
// 6. z = (g@Wmu + bmu) + noise * exp(g@Wls + bls); Wmu,Wls [128x64] in LDS.
// ---------------------------------------------------------------------------
__global__ __launch_bounds__(256) void k_gemm_z(const float* __restrict__ g,
                                                const float* __restrict__ Wmu,
                                                const float* __restrict__ bmu,
                                                const float* __restrict__ Wls,
                                                const float* __restrict__ bls,
                                                const float* __restrict__ noise,
                                                float* __restrict__ z) {
    __shared__ float lw[2 * D_ * O_];        // 64 KiB total
    for (int t = threadIdx.x; t < D_ * O_ / 4; t += 256) {
        ((float4*)lw)[t]                 = ((const float4*)Wmu)[t];
        ((float4*)lw)[t + D_ * O_ / 4]   = ((const float4*)Wls)[t];
    }
    __syncthreads();
    int sub = threadIdx.x >> 5, l = threadIdx.x & 31;
    float2 bm = ((const float2*)bmu)[l];
    float2 bl = ((const float2*)bls)[l];
    for (int row = blockIdx.x * 8 + sub; row < N_; row += gridDim.x * 8) {
        const float* gr = g + (size_t)row * D_;
        float2 am = {0.f, 0.f}, al = {0.f, 0.f};
#pragma unroll 4
        for (int k = 0; k < D_; ++k) {
            float gv = gr[k];
            float2 wm = ((const float2*)lw)[k * 32 + l];
            float2 wl = ((const float2*)(lw + D_ * O_))[k * 32 + l];
            am.x = fmaf(gv, wm.x, am.x); am.y = fmaf(gv, wm.y, am.y);
            al.x = fmaf(gv, wl.x, al.x); al.y = fmaf(gv, wl.y, al.y);
        }
        float2 nz = ((const float2*)(noise + (size_t)row * O_))[l];
        float2 zz;
        zz.x = (am.x + bm.x) + nz.x * expf(al.x + bl.x);
        zz.y = (am.y + bm.y) + nz.y * expf(al.y + bl.y);
        ((float2*)(z + (size_t)row * O_))[l] = zz;
    }
}

// ---------------------------------------------------------------------------
// 7. Decoder: logits[e] = dot(z[src], z[dst]) over 64. 16 lanes per edge.
// ---------------------------------------------------------------------------
__global__ __launch_bounds__(256) void k_decode(const int* __restrict__ src,
                                                const int* __restrict__ dst,
                                                const float* __restrict__ z,
                                                float* __restrict__ out) {
    int e = blockIdx.x * 16 + (threadIdx.x >> 4);
    if (e >= E_) return;
    int l = threadIdx.x & 15;
    int s = src[e], d = dst[e];
    float4 a = ((const float4*)(z + (size_t)s * O_))[l];
    float4 b = ((const float4*)(z + (size_t)d * O_))[l];
    float p = a.x * b.x + a.y * b.y + a.z * b.z + a.w * b.w;
#pragma unroll
    for (int o = 8; o; o >>= 1) p += __shfl_xor(p, o);
    if (l == 0) out[e] = p;
}

// ---------------------------------------------------------------------------
extern "C" void kernel_launch(void* const* d_in, const int* in_sizes, int n_in,
                              void* d_out, int out_size, void* d_ws, size_t ws_size,
                              hipStream_t stream) {
    const int*   fi    = (const int*)d_in[0];
    // d_in[1] = feature_offsets: known to be n*16, unused.
    const float* fw    = (const float*)d_in[2];
    const int*   ei    = (const int*)d_in[3];
    const float* noise = (const float*)d_in[4];
    const float* emb   = (const float*)d_in[5];
    const float* W1    = (const float*)d_in[6];
    const float* b1    = (const float*)d_in[7];
    const float* Wmu   = (const float*)d_in[8];
    const float* bmu   = (const float*)d_in[9];
    const float* Wls   = (const float*)d_in[10];
    const float* bls   = (const float*)d_in[11];
    float* out = (float*)d_out;

    const int* src = ei;
    const int* dst = ei + E_;

    float* ws   = (float*)d_ws;
    float* x    = ws;                          // N*128
    float* agg  = x   + (size_t)N_ * D_;       // N*128 (reused for both GCN aggs)
    float* h    = agg + (size_t)N_ * D_;       // N*128
    float* z    = h   + (size_t)N_ * D_;       // N*64
    float* cnt  = z   + (size_t)N_ * O_;       // N
    float* disq = cnt + N_;                    // N
    float* dinv = disq + N_;                   // N

    hipMemsetAsync(cnt, 0, N_ * sizeof(float), stream);

    k_embed  <<<N_ / 4,            256, 0, stream>>>(fi, fw, emb, x);
    k_degcnt <<<(E_ + 255) / 256,  256, 0, stream>>>(dst, cnt);
    k_degnorm<<<(N_ + 255) / 256,  256, 0, stream>>>(cnt, disq, dinv);

    // GCN layer 1: agg_x (+self term) -> h = relu(agg @ W1 + b1)
    k_initagg<<<N_ * (D_ / 4) / 256, 256, 0, stream>>>(x, dinv, agg);
    k_scatter<<<E_ / 8,             256, 0, stream>>>(src, dst, disq, x, agg);
    k_gemm_relu<<<1024,             256, 0, stream>>>(agg, W1, b1, h);

    // GCN layers 2+3 share one aggregation of h
    k_initagg<<<N_ * (D_ / 4) / 256, 256, 0, stream>>>(h, dinv, agg);
    k_scatter<<<E_ / 8,             256, 0, stream>>>(src, dst, disq, h, agg);
    k_gemm_z <<<1024,               256, 0, stream>>>(agg, Wmu, bmu, Wls, bls, noise, z);

    // Decoder
    k_decode <<<E_ / 16,            256, 0, stream>>>(src, dst, z, out);
}

// Round 2
// 920.543 us; speedup vs baseline: 6.3948x; 6.3948x over previous
//
#include <hip/hip_runtime.h>

// VGAE forward, MI355X. All fp32. Gather-based (deterministic) GCN aggregation.
constexpr int N_ = 50000;
constexpr int E_ = 1600000;
constexpr int D_ = 128;   // embedding_dim == hidden_dim
constexpr int O_ = 64;    // out_embedding_dim
constexpr int NNZ_ = 16;

// ---------------------------------------------------------------------------
// 1. EmbeddingBag(sum, per_sample_weights) + L2 normalize. One wave per node.
// ---------------------------------------------------------------------------
__global__ __launch_bounds__(256) void k_embed(const int* __restrict__ fi,
                                               const float* __restrict__ fw,
                                               const float* __restrict__ emb,
                                               float* __restrict__ x) {
    int n = blockIdx.x * 4 + (threadIdx.x >> 6);
    if (n >= N_) return;
    int lane = threadIdx.x & 63;
    float a0 = 0.f, a1 = 0.f;
    int base = n * NNZ_;
#pragma unroll
    for (int j = 0; j < NNZ_; ++j) {
        int idx  = fi[base + j];
        float w  = fw[base + j];
        const float* r = emb + (size_t)idx * D_;
        a0 = fmaf(w, r[lane], a0);
        a1 = fmaf(w, r[lane + 64], a1);
    }
    float ss = a0 * a0 + a1 * a1;
#pragma unroll
    for (int o = 32; o; o >>= 1) ss += __shfl_xor(ss, o);
    float sc = 1.0f / fmaxf(sqrtf(ss), 1e-12f);
    x[(size_t)n * D_ + lane]      = a0 * sc;
    x[(size_t)n * D_ + lane + 64] = a1 * sc;
}

// ---------------------------------------------------------------------------
// 2. In-degree histogram (int atomics) + normalization factors
// ---------------------------------------------------------------------------
__global__ __launch_bounds__(256) void k_degcnt(const int* __restrict__ dst,
                                                int* __restrict__ cnt) {
    int e = blockIdx.x * blockDim.x + threadIdx.x;
    if (e < E_) atomicAdd(&cnt[dst[e]], 1);
}

__global__ __launch_bounds__(256) void k_degnorm(const int* __restrict__ cnt,
                                                 float* __restrict__ disq,
                                                 float* __restrict__ dinv) {
    int n = blockIdx.x * blockDim.x + threadIdx.x;
    if (n < N_) {
        float deg = 1.0f + (float)cnt[n];
        disq[n] = rsqrtf(deg);
        dinv[n] = 1.0f / deg;
    }
}

// ---------------------------------------------------------------------------
// 3. Exclusive prefix scan of cnt[N] -> row_start[N+1]. Single 256-thread block.
// ---------------------------------------------------------------------------
__global__ __launch_bounds__(256) void k_scan(const int* __restrict__ cnt,
                                              int* __restrict__ row_start) {
    __shared__ int sums[256];
    const int chunk = (N_ + 255) / 256;          // 196
    int t = threadIdx.x;
    int begin = t * chunk;
    int end   = begin + chunk; if (end > N_) end = N_;
    int s = 0;
    for (int i = begin; i < end; ++i) s += cnt[i];
    sums[t] = s;
    __syncthreads();
    // inclusive Hillis-Steele scan over 256 partials
    for (int o = 1; o < 256; o <<= 1) {
        int v = (t >= o) ? sums[t - o] : 0;
        __syncthreads();
        sums[t] += v;
        __syncthreads();
    }
    int run = t ? sums[t - 1] : 0;               // exclusive prefix of my chunk
    for (int i = begin; i < end; ++i) { row_start[i] = run; run += cnt[i]; }
    if (t == 255) row_start[N_] = run;
}

// ---------------------------------------------------------------------------
// 4. CSR fill: bucket edges by dst; store src id and precomputed edge weight.
// ---------------------------------------------------------------------------
__global__ __launch_bounds__(256) void k_fill(const int* __restrict__ src,
                                              const int* __restrict__ dst,
                                              const float* __restrict__ disq,
                                              const int* __restrict__ row_start,
                                              int* __restrict__ cursor,
                                              int* __restrict__ sorted_src,
                                              float* __restrict__ sorted_w) {
    int e = blockIdx.x * blockDim.x + threadIdx.x;
    if (e >= E_) return;
    int s = src[e], d = dst[e];
    int pos = row_start[d] + atomicAdd(&cursor[d], 1);
    sorted_src[pos] = s;
    sorted_w[pos]   = disq[s] * disq[d];
}

// ---------------------------------------------------------------------------
// 5. Gather aggregation: agg[n] = dinv[n]*v[n] + sum_j w_j * v[src_j]  (D=128)
//    One wave per node, float2 per lane (64 lanes * 8B = full 512B row).
// ---------------------------------------------------------------------------
__global__ __launch_bounds__(256) void k_gather(const int* __restrict__ row_start,
                                                const int* __restrict__ sorted_src,
                                                const float* __restrict__ sorted_w,
                                                const float* __restrict__ dinv,
                                                const float* __restrict__ v,
                                                float* __restrict__ agg) {
    int n = blockIdx.x * 4 + (threadIdx.x >> 6);
    if (n >= N_) return;
    int lane = threadIdx.x & 63;
    const float2* V = (const float2*)v;
    int beg = row_start[n], end = row_start[n + 1];
    float ax = 0.f, ay = 0.f;
    int j = beg;
    // 4x unroll for memory-level parallelism
    for (; j + 3 < end; j += 4) {
        int   s0 = sorted_src[j],     s1 = sorted_src[j + 1];
        int   s2 = sorted_src[j + 2], s3 = sorted_src[j + 3];
        float w0 = sorted_w[j],       w1 = sorted_w[j + 1];
        float w2 = sorted_w[j + 2],   w3 = sorted_w[j + 3];
        float2 a0 = V[(size_t)s0 * 64 + lane];
        float2 a1 = V[(size_t)s1 * 64 + lane];
        float2 a2 = V[(size_t)s2 * 64 + lane];
        float2 a3 = V[(size_t)s3 * 64 + lane];
        ax = fmaf(w0, a0.x, ax); ay = fmaf(w0, a0.y, ay);
        ax = fmaf(w1, a1.x, ax); ay = fmaf(w1, a1.y, ay);
        ax = fmaf(w2, a2.x, ax); ay = fmaf(w2, a2.y, ay);
        ax = fmaf(w3, a3.x, ax); ay = fmaf(w3, a3.y, ay);
    }
    for (; j < end; ++j) {
        int s = sorted_src[j];
        float w = sorted_w[j];
        float2 a = V[(size_t)s * 64 + lane];
        ax = fmaf(w, a.x, ax); ay = fmaf(w, a.y, ay);
    }
    float di = dinv[n];
    float2 self = V[(size_t)n * 64 + lane];
    ax = fmaf(di, self.x, ax);
    ay = fmaf(di, self.y, ay);
    ((float2*)agg)[(size_t)n * 64 + lane] = make_float2(ax, ay);
}

// ---------------------------------------------------------------------------
// 6. h = relu(u @ W1 + b1), W1 [128x128] staged in LDS.
// ---------------------------------------------------------------------------
__global__ __launch_bounds__(256) void k_gemm_relu(const float* __restrict__ u,
                                                   const float* __restrict__ W,
                                                   const float* __restrict__ b,
                                                   float* __restrict__ h) {
    __shared__ float lw[D_ * D_];            // 64 KiB
    for (int t = threadIdx.x; t < D_ * D_ / 4; t += 256)
        ((float4*)lw)[t] = ((const float4*)W)[t];
    __syncthreads();
    int sub = threadIdx.x >> 5, l = threadIdx.x & 31;
    float4 bb = ((const float4*)b)[l];
    for (int row = blockIdx.x * 8 + sub; row < N_; row += gridDim.x * 8) {
        const float* ur = u + (size_t)row * D_;
        float4 acc = {0.f, 0.f, 0.f, 0.f};
#pragma unroll 4
        for (int k = 0; k < D_; ++k) {
            float uv = ur[k];
            float4 w = ((const float4*)lw)[k * 32 + l];
            acc.x = fmaf(uv, w.x, acc.x);
            acc.y = fmaf(uv, w.y, acc.y);
            acc.z = fmaf(uv, w.z, acc.z);
            acc.w = fmaf(uv, w.w, acc.w);
        }
        acc.x = fmaxf(acc.x + bb.x, 0.f);
        acc.y = fmaxf(acc.y + bb.y, 0.f);
        acc.z = fmaxf(acc.z + bb.z, 0.f);
        acc.w = fmaxf(acc.w + bb.w, 0.f);
        ((float4*)(h + (size_t)row * D_))[l] = acc;
    }
}

// ---------------------------------------------------------------------------
// 7. z = (g@Wmu + bmu) + noise * exp(g@Wls + bls); Wmu,Wls [128x64] in LDS.
// ---------------------------------------------------------------------------
__global__ __launch_bounds__(256) void k_gemm_z(const float* __restrict__ g,
                                                const float* __restrict__ Wmu,
                                                const float* __restrict__ bmu,
                                                const float* __restrict__ Wls,
                                                const float* __restrict__ bls,
                                                const float* __restrict__ noise,
                                                float* __restrict__ z) {
    __shared__ float lw[2 * D_ * O_];        // 64 KiB total
    for (int t = threadIdx.x; t < D_ * O_ / 4; t += 256) {
        ((float4*)lw)[t]                 = ((const float4*)Wmu)[t];
        ((float4*)lw)[t + D_ * O_ / 4]   = ((const float4*)Wls)[t];
    }
    __syncthreads();
    int sub = threadIdx.x >> 5, l = threadIdx.x & 31;
    float2 bm = ((const float2*)bmu)[l];
    float2 bl = ((const float2*)bls)[l];
    for (int row = blockIdx.x * 8 + sub; row < N_; row += gridDim.x * 8) {
        const float* gr = g + (size_t)row * D_;
        float2 am = {0.f, 0.f}, al = {0.f, 0.f};
#pragma unroll 4
        for (int k = 0; k < D_; ++k) {
            float gv = gr[k];
            float2 wm = ((const float2*)lw)[k * 32 + l];
            float2 wl = ((const float2*)(lw + D_ * O_))[k * 32 + l];
            am.x = fmaf(gv, wm.x, am.x); am.y = fmaf(gv, wm.y, am.y);
            al.x = fmaf(gv, wl.x, al.x); al.y = fmaf(gv, wl.y, al.y);
        }
        float2 nz = ((const float2*)(noise + (size_t)row * O_))[l];
        float2 zz;
        zz.x = (am.x + bm.x) + nz.x * expf(al.x + bl.x);
        zz.y = (am.y + bm.y) + nz.y * expf(al.y + bl.y);
        ((float2*)(z + (size_t)row * O_))[l] = zz;
    }
}

// ---------------------------------------------------------------------------
// 8. Decoder: logits[e] = dot(z[src], z[dst]) over 64. 16 lanes per edge.
// ---------------------------------------------------------------------------
__global__ __launch_bounds__(256) void k_decode(const int* __restrict__ src,
                                                const int* __restrict__ dst,
                                                const float* __restrict__ z,
                                                float* __restrict__ out) {
    int e = blockIdx.x * 16 + (threadIdx.x >> 4);
    if (e >= E_) return;
    int l = threadIdx.x & 15;
    int s = src[e], d = dst[e];
    float4 a = ((const float4*)(z + (size_t)s * O_))[l];
    float4 b = ((const float4*)(z + (size_t)d * O_))[l];
    float p = a.x * b.x + a.y * b.y + a.z * b.z + a.w * b.w;
#pragma unroll
    for (int o = 8; o; o >>= 1) p += __shfl_xor(p, o);
    if (l == 0) out[e] = p;
}

// ---------------------------------------------------------------------------
extern "C" void kernel_launch(void* const* d_in, const int* in_sizes, int n_in,
                              void* d_out, int out_size, void* d_ws, size_t ws_size,
                              hipStream_t stream) {
    const int*   fi    = (const int*)d_in[0];
    // d_in[1] = feature_offsets: known to be n*16, unused.
    const float* fw    = (const float*)d_in[2];
    const int*   ei    = (const int*)d_in[3];
    const float* noise = (const float*)d_in[4];
    const float* emb   = (const float*)d_in[5];
    const float* W1    = (const float*)d_in[6];
    const float* b1    = (const float*)d_in[7];
    const float* Wmu   = (const float*)d_in[8];
    const float* bmu   = (const float*)d_in[9];
    const float* Wls   = (const float*)d_in[10];
    const float* bls   = (const float*)d_in[11];
    float* out = (float*)d_out;

    const int* src = ei;
    const int* dst = ei + E_;

    // Workspace layout
    float* ws       = (float*)d_ws;
    float* x        = ws;                            // N*128
    float* agg      = x    + (size_t)N_ * D_;        // N*128
    float* h        = agg  + (size_t)N_ * D_;        // N*128
    float* z        = h    + (size_t)N_ * D_;        // N*64
    float* disq     = z    + (size_t)N_ * O_;        // N
    float* dinv     = disq + N_;                     // N
    float* sorted_w = dinv + N_;                     // E
    int*   cnt      = (int*)(sorted_w + E_);         // N
    int*   cursor   = cnt + N_;                      // N
    int*   row_start= cursor + N_;                   // N+1
    int*   sorted_src = row_start + (N_ + 1);        // E

    // zero histogram + cursors (adjacent) in one memset
    hipMemsetAsync(cnt, 0, 2 * N_ * sizeof(int), stream);

    k_embed  <<<N_ / 4,            256, 0, stream>>>(fi, fw, emb, x);
    k_degcnt <<<(E_ + 255) / 256,  256, 0, stream>>>(dst, cnt);
    k_degnorm<<<(N_ + 255) / 256,  256, 0, stream>>>(cnt, disq, dinv);
    k_scan   <<<1,                 256, 0, stream>>>(cnt, row_start);
    k_fill   <<<(E_ + 255) / 256,  256, 0, stream>>>(src, dst, disq, row_start,
                                                     cursor, sorted_src, sorted_w);

    // GCN layer 1: gather(x) -> h = relu(agg @ W1 + b1)
    k_gather <<<N_ / 4,            256, 0, stream>>>(row_start, sorted_src, sorted_w,
                                                    dinv, x, agg);
    k_gemm_relu<<<1024,            256, 0, stream>>>(agg, W1, b1, h);

    // GCN layers 2+3 share one gather of h
    k_gather <<<N_ / 4,            256, 0, stream>>>(row_start, sorted_src, sorted_w,
                                                    dinv, h, agg);
    k_gemm_z <<<1024,              256, 0, stream>>>(agg, Wmu, bmu, Wls, bls, noise, z);

    // Decoder
    k_decode <<<E_ / 16,           256, 0, stream>>>(src, dst, z, out);
}

// Round 3
// 690.726 us; speedup vs baseline: 8.5225x; 1.3327x over previous
//
#include <hip/hip_runtime.h>
#include <hip/hip_bf16.h>

// VGAE forward, MI355X. Gather-based GCN; bf16 storage for gathered operands.
constexpr int N_ = 50000;
constexpr int E_ = 1600000;
constexpr int D_ = 128;   // embedding_dim == hidden_dim
constexpr int O_ = 64;    // out_embedding_dim
constexpr int NNZ_ = 16;

static __device__ __forceinline__ unsigned short f2bf(float f) {
    __hip_bfloat16 h = __float2bfloat16(f);
    return __builtin_bit_cast(unsigned short, h);
}
static __device__ __forceinline__ float blo(unsigned int u) { return __uint_as_float(u << 16); }
static __device__ __forceinline__ float bhi(unsigned int u) { return __uint_as_float(u & 0xffff0000u); }
static __device__ __forceinline__ float4 fma4(float s, float4 a, float4 b) {
    return make_float4(fmaf(s, a.x, b.x), fmaf(s, a.y, b.y),
                       fmaf(s, a.z, b.z), fmaf(s, a.w, b.w));
}

// ---------------------------------------------------------------------------
// 1. EmbeddingBag(sum) + L2 normalize. One wave per node. Writes x as bf16.
//    Lane owns dims (2l, 2l+1) -> one packed u32 per lane.
// ---------------------------------------------------------------------------
__global__ __launch_bounds__(256) void k_embed(const int* __restrict__ fi,
                                               const float* __restrict__ fw,
                                               const float* __restrict__ emb,
                                               unsigned int* __restrict__ x) {
    int n = blockIdx.x * 4 + (threadIdx.x >> 6);
    if (n >= N_) return;
    int lane = threadIdx.x & 63;
    float a0 = 0.f, a1 = 0.f;
    int base = n * NNZ_;
#pragma unroll
    for (int j = 0; j < NNZ_; ++j) {
        int idx  = fi[base + j];
        float w  = fw[base + j];
        float2 r = ((const float2*)(emb + (size_t)idx * D_))[lane];
        a0 = fmaf(w, r.x, a0);
        a1 = fmaf(w, r.y, a1);
    }
    float ss = a0 * a0 + a1 * a1;
#pragma unroll
    for (int o = 32; o; o >>= 1) ss += __shfl_xor(ss, o);
    float sc = 1.0f / fmaxf(sqrtf(ss), 1e-12f);
    x[(size_t)n * 64 + lane] =
        (unsigned int)f2bf(a0 * sc) | ((unsigned int)f2bf(a1 * sc) << 16);
}

// ---------------------------------------------------------------------------
// 2. In-degree histogram + normalization factors
// ---------------------------------------------------------------------------
__global__ __launch_bounds__(256) void k_degcnt(const int* __restrict__ dst,
                                                int* __restrict__ cnt) {
    int e = blockIdx.x * blockDim.x + threadIdx.x;
    if (e < E_) atomicAdd(&cnt[dst[e]], 1);
}

__global__ __launch_bounds__(256) void k_degnorm(const int* __restrict__ cnt,
                                                 float* __restrict__ disq,
                                                 float* __restrict__ dinv) {
    int n = blockIdx.x * blockDim.x + threadIdx.x;
    if (n < N_) {
        float deg = 1.0f + (float)cnt[n];
        disq[n] = rsqrtf(deg);
        dinv[n] = 1.0f / deg;
    }
}

// ---------------------------------------------------------------------------
// 3. Exclusive prefix scan of cnt[N] -> row_start[N+1]. Single block.
// ---------------------------------------------------------------------------
__global__ __launch_bounds__(256) void k_scan(const int* __restrict__ cnt,
                                              int* __restrict__ row_start) {
    __shared__ int sums[256];
    const int chunk = (N_ + 255) / 256;
    int t = threadIdx.x;
    int begin = t * chunk;
    int end   = begin + chunk; if (end > N_) end = N_;
    int s = 0;
    for (int i = begin; i < end; ++i) s += cnt[i];
    sums[t] = s;
    __syncthreads();
    for (int o = 1; o < 256; o <<= 1) {
        int v = (t >= o) ? sums[t - o] : 0;
        __syncthreads();
        sums[t] += v;
        __syncthreads();
    }
    int run = t ? sums[t - 1] : 0;
    for (int i = begin; i < end; ++i) { row_start[i] = run; run += cnt[i]; }
    if (t == 255) row_start[N_] = run;
}

// ---------------------------------------------------------------------------
// 4. CSR fill by dst; store src id and precomputed edge weight.
// ---------------------------------------------------------------------------
__global__ __launch_bounds__(256) void k_fill(const int* __restrict__ src,
                                              const int* __restrict__ dst,
                                              const float* __restrict__ disq,
                                              const int* __restrict__ row_start,
                                              int* __restrict__ cursor,
                                              int* __restrict__ sorted_src,
                                              float* __restrict__ sorted_w) {
    int e = blockIdx.x * blockDim.x + threadIdx.x;
    if (e >= E_) return;
    int s = src[e], d = dst[e];
    int pos = row_start[d] + atomicAdd(&cursor[d], 1);
    sorted_src[pos] = s;
    sorted_w[pos]   = disq[s] * disq[d];
}

// ---------------------------------------------------------------------------
// 5. Gather aggregation from bf16 rows: agg[n] = dinv[n]*v[n] + sum w_j*v[src_j]
//    One wave per node; lane reads one u32 (2 bf16) = full 256B row per wave.
//    Output agg is fp32 [N][128].
// ---------------------------------------------------------------------------
__global__ __launch_bounds__(256) void k_gather(const int* __restrict__ row_start,
                                                const int* __restrict__ sorted_src,
                                                const float* __restrict__ sorted_w,
                                                const float* __restrict__ dinv,
                                                const unsigned int* __restrict__ v,
                                                float* __restrict__ agg) {
    int n = blockIdx.x * 4 + (threadIdx.x >> 6);
    if (n >= N_) return;
    int lane = threadIdx.x & 63;
    int beg = row_start[n], end = row_start[n + 1];
    float ax = 0.f, ay = 0.f;
    int j = beg;
    for (; j + 3 < end; j += 4) {
        int   s0 = sorted_src[j],     s1 = sorted_src[j + 1];
        int   s2 = sorted_src[j + 2], s3 = sorted_src[j + 3];
        float w0 = sorted_w[j],       w1 = sorted_w[j + 1];
        float w2 = sorted_w[j + 2],   w3 = sorted_w[j + 3];
        unsigned int b0 = v[(size_t)s0 * 64 + lane];
        unsigned int b1 = v[(size_t)s1 * 64 + lane];
        unsigned int b2 = v[(size_t)s2 * 64 + lane];
        unsigned int b3 = v[(size_t)s3 * 64 + lane];
        ax = fmaf(w0, blo(b0), ax); ay = fmaf(w0, bhi(b0), ay);
        ax = fmaf(w1, blo(b1), ax); ay = fmaf(w1, bhi(b1), ay);
        ax = fmaf(w2, blo(b2), ax); ay = fmaf(w2, bhi(b2), ay);
        ax = fmaf(w3, blo(b3), ax); ay = fmaf(w3, bhi(b3), ay);
    }
    for (; j < end; ++j) {
        int s = sorted_src[j];
        float w = sorted_w[j];
        unsigned int b = v[(size_t)s * 64 + lane];
        ax = fmaf(w, blo(b), ax); ay = fmaf(w, bhi(b), ay);
    }
    float di = dinv[n];
    unsigned int bs = v[(size_t)n * 64 + lane];
    ax = fmaf(di, blo(bs), ax);
    ay = fmaf(di, bhi(bs), ay);
    ((float2*)agg)[(size_t)n * 64 + lane] = make_float2(ax, ay);
}

// ---------------------------------------------------------------------------
// 6. Register-blocked GEMM: h = relu(agg @ W1 + b1), bf16 output.
//    W (64KB) + 32-row tile (16KB) in LDS = 80KB -> 2 blocks/CU.
//    Wave: 8 rows x 128 cols; lane: 4 rows x float4 cols; VALU-bound.
// ---------------------------------------------------------------------------
__global__ __launch_bounds__(256, 2) void k_gemm_relu(const float* __restrict__ u,
                                                      const float* __restrict__ W,
                                                      const float* __restrict__ b,
                                                      unsigned short* __restrict__ hout) {
    __shared__ float lw[D_ * D_];     // 64 KiB
    __shared__ float lu[32 * D_];     // 16 KiB
    int tid = threadIdx.x;
    for (int t = tid; t < D_ * D_ / 4; t += 256)
        ((float4*)lw)[t] = ((const float4*)W)[t];

    int l  = tid & 31;
    int rl = ((tid >> 6) << 3) + (((tid >> 5) & 1) << 2);   // wave*8 + half*4
    float4 bb = ((const float4*)b)[l];

    for (int tile = blockIdx.x; tile * 32 < N_; tile += gridDim.x) {
        int row0 = tile * 32;
        __syncthreads();
#pragma unroll
        for (int i = 0; i < 4; ++i) {
            int flat = i * 256 + tid;        // 0..1023 float4 slots
            int r = flat >> 5, c4 = flat & 31;
            int gr = row0 + r;
            ((float4*)lu)[flat] = (gr < N_) ? ((const float4*)u)[(size_t)gr * 32 + c4]
                                            : make_float4(0.f, 0.f, 0.f, 0.f);
        }
        __syncthreads();
        float4 a0 = {0,0,0,0}, a1 = {0,0,0,0}, a2 = {0,0,0,0}, a3 = {0,0,0,0};
#pragma unroll 4
        for (int k4 = 0; k4 < 32; ++k4) {
            int k = k4 * 4;
            float4 w0 = ((const float4*)(lw + (k + 0) * D_))[l];
            float4 w1 = ((const float4*)(lw + (k + 1) * D_))[l];
            float4 w2 = ((const float4*)(lw + (k + 2) * D_))[l];
            float4 w3 = ((const float4*)(lw + (k + 3) * D_))[l];
            float4 u0 = ((const float4*)(lu + (rl + 0) * D_))[k4];
            float4 u1 = ((const float4*)(lu + (rl + 1) * D_))[k4];
            float4 u2 = ((const float4*)(lu + (rl + 2) * D_))[k4];
            float4 u3 = ((const float4*)(lu + (rl + 3) * D_))[k4];
            a0 = fma4(u0.x, w0, fma4(u0.y, w1, fma4(u0.z, w2, fma4(u0.w, w3, a0))));
            a1 = fma4(u1.x, w0, fma4(u1.y, w1, fma4(u1.z, w2, fma4(u1.w, w3, a1))));
            a2 = fma4(u2.x, w0, fma4(u2.y, w1, fma4(u2.z, w2, fma4(u2.w, w3, a2))));
            a3 = fma4(u3.x, w0, fma4(u3.y, w1, fma4(u3.z, w2, fma4(u3.w, w3, a3))));
        }
        float4 accs[4] = {a0, a1, a2, a3};
#pragma unroll
        for (int r = 0; r < 4; ++r) {
            int row = row0 + rl + r;
            if (row < N_) {
                float4 a = accs[r];
                ushort4 o;
                o.x = f2bf(fmaxf(a.x + bb.x, 0.f));
                o.y = f2bf(fmaxf(a.y + bb.y, 0.f));
                o.z = f2bf(fmaxf(a.z + bb.z, 0.f));
                o.w = f2bf(fmaxf(a.w + bb.w, 0.f));
                ((ushort4*)hout)[(size_t)row * 32 + l] = o;
            }
        }
    }
}

// ---------------------------------------------------------------------------
// 7. Fused mu/logstd GEMM: columns interleaved (2j=mu_j, 2j+1=ls_j) -> one
//    128-wide GEMM; epilogue z = mu + noise*exp(ls), bf16 output.
// ---------------------------------------------------------------------------
__global__ __launch_bounds__(256, 2) void k_gemm_z(const float* __restrict__ g,
                                                   const float* __restrict__ Wmu,
                                                   const float* __restrict__ bmu,
                                                   const float* __restrict__ Wls,
                                                   const float* __restrict__ bls,
                                                   const float* __restrict__ noise,
                                                   unsigned int* __restrict__ z) {
    __shared__ float lw[D_ * D_];     // 64 KiB (interleaved Wmu|Wls)
    __shared__ float lu[32 * D_];     // 16 KiB
    int tid = threadIdx.x;
    for (int t = tid; t < D_ * 32; t += 256) {          // 4096 float4 slots
        int k = t >> 5, j2 = t & 31;                    // j2 -> out pairs 2j2, 2j2+1
        float2 m2 = ((const float2*)Wmu)[k * 32 + j2];
        float2 l2 = ((const float2*)Wls)[k * 32 + j2];
        ((float4*)lw)[t] = make_float4(m2.x, l2.x, m2.y, l2.y);
    }

    int l  = tid & 31;
    int rl = ((tid >> 6) << 3) + (((tid >> 5) & 1) << 2);
    float2 bm = ((const float2*)bmu)[l];
    float2 bl = ((const float2*)bls)[l];
    float4 bb = make_float4(bm.x, bl.x, bm.y, bl.y);

    for (int tile = blockIdx.x; tile * 32 < N_; tile += gridDim.x) {
        int row0 = tile * 32;
        __syncthreads();
#pragma unroll
        for (int i = 0; i < 4; ++i) {
            int flat = i * 256 + tid;
            int r = flat >> 5, c4 = flat & 31;
            int gr = row0 + r;
            ((float4*)lu)[flat] = (gr < N_) ? ((const float4*)g)[(size_t)gr * 32 + c4]
                                            : make_float4(0.f, 0.f, 0.f, 0.f);
        }
        __syncthreads();
        float4 a0 = {0,0,0,0}, a1 = {0,0,0,0}, a2 = {0,0,0,0}, a3 = {0,0,0,0};
#pragma unroll 4
        for (int k4 = 0; k4 < 32; ++k4) {
            int k = k4 * 4;
            float4 w0 = ((const float4*)(lw + (k + 0) * D_))[l];
            float4 w1 = ((const float4*)(lw + (k + 1) * D_))[l];
            float4 w2 = ((const float4*)(lw + (k + 2) * D_))[l];
            float4 w3 = ((const float4*)(lw + (k + 3) * D_))[l];
            float4 u0 = ((const float4*)(lu + (rl + 0) * D_))[k4];
            float4 u1 = ((const float4*)(lu + (rl + 1) * D_))[k4];
            float4 u2 = ((const float4*)(lu + (rl + 2) * D_))[k4];
            float4 u3 = ((const float4*)(lu + (rl + 3) * D_))[k4];
            a0 = fma4(u0.x, w0, fma4(u0.y, w1, fma4(u0.z, w2, fma4(u0.w, w3, a0))));
            a1 = fma4(u1.x, w0, fma4(u1.y, w1, fma4(u1.z, w2, fma4(u1.w, w3, a1))));
            a2 = fma4(u2.x, w0, fma4(u2.y, w1, fma4(u2.z, w2, fma4(u2.w, w3, a2))));
            a3 = fma4(u3.x, w0, fma4(u3.y, w1, fma4(u3.z, w2, fma4(u3.w, w3, a3))));
        }
        float4 accs[4] = {a0, a1, a2, a3};
#pragma unroll
        for (int r = 0; r < 4; ++r) {
            int row = row0 + rl + r;
            if (row < N_) {
                float4 a = accs[r];
                float2 n2 = ((const float2*)noise)[(size_t)row * 32 + l];
                float z0 = (a.x + bb.x) + n2.x * expf(a.y + bb.y);
                float z1 = (a.z + bb.z) + n2.y * expf(a.w + bb.w);
                z[(size_t)row * 32 + l] =
                    (unsigned int)f2bf(z0) | ((unsigned int)f2bf(z1) << 16);
            }
        }
    }
}

// ---------------------------------------------------------------------------
// 8. Decoder: logits[e] = dot(z[src], z[dst]) over 64 bf16. 16 lanes per edge.
// ---------------------------------------------------------------------------
__global__ __launch_bounds__(256) void k_decode(const int* __restrict__ src,
                                                const int* __restrict__ dst,
                                                const unsigned int* __restrict__ z,
                                                float* __restrict__ out) {
    int e = blockIdx.x * 16 + (threadIdx.x >> 4);
    if (e >= E_) return;
    int l = threadIdx.x & 15;
    int s = src[e], d = dst[e];
    uint2 za = ((const uint2*)z)[(size_t)s * 16 + l];
    uint2 zb = ((const uint2*)z)[(size_t)d * 16 + l];
    float p = blo(za.x) * blo(zb.x) + bhi(za.x) * bhi(zb.x)
            + blo(za.y) * blo(zb.y) + bhi(za.y) * bhi(zb.y);
#pragma unroll
    for (int o = 8; o; o >>= 1) p += __shfl_xor(p, o);
    if (l == 0) out[e] = p;
}

// ---------------------------------------------------------------------------
extern "C" void kernel_launch(void* const* d_in, const int* in_sizes, int n_in,
                              void* d_out, int out_size, void* d_ws, size_t ws_size,
                              hipStream_t stream) {
    const int*   fi    = (const int*)d_in[0];
    const float* fw    = (const float*)d_in[2];
    const int*   ei    = (const int*)d_in[3];
    const float* noise = (const float*)d_in[4];
    const float* emb   = (const float*)d_in[5];
    const float* W1    = (const float*)d_in[6];
    const float* b1    = (const float*)d_in[7];
    const float* Wmu   = (const float*)d_in[8];
    const float* bmu   = (const float*)d_in[9];
    const float* Wls   = (const float*)d_in[10];
    const float* bls   = (const float*)d_in[11];
    float* out = (float*)d_out;

    const int* src = ei;
    const int* dst = ei + E_;

    // Workspace layout (4-byte units)
    float*        ws        = (float*)d_ws;
    float*        agg       = ws;                                  // N*128 f32
    unsigned int* x         = (unsigned int*)(agg + (size_t)N_ * D_); // N*64 u32 (bf16x2)
    unsigned int* h         = x + (size_t)N_ * 64;                 // N*64 u32
    unsigned int* z         = h + (size_t)N_ * 64;                 // N*32 u32
    float*        disq      = (float*)(z + (size_t)N_ * 32);       // N
    float*        dinv      = disq + N_;                           // N
    float*        sorted_w  = dinv + N_;                           // E
    int*          cnt       = (int*)(sorted_w + E_);               // N
    int*          cursor    = cnt + N_;                            // N
    int*          row_start = cursor + N_;                         // N+1
    int*          sorted_src= row_start + (N_ + 1);                // E

    hipMemsetAsync(cnt, 0, 2 * N_ * sizeof(int), stream);

    k_embed  <<<N_ / 4,            256, 0, stream>>>(fi, fw, emb, x);
    k_degcnt <<<(E_ + 255) / 256,  256, 0, stream>>>(dst, cnt);
    k_degnorm<<<(N_ + 255) / 256,  256, 0, stream>>>(cnt, disq, dinv);
    k_scan   <<<1,                 256, 0, stream>>>(cnt, row_start);
    k_fill   <<<(E_ + 255) / 256,  256, 0, stream>>>(src, dst, disq, row_start,
                                                     cursor, sorted_src, sorted_w);

    // GCN layer 1
    k_gather   <<<N_ / 4, 256, 0, stream>>>(row_start, sorted_src, sorted_w, dinv, x, agg);
    k_gemm_relu<<<512,    256, 0, stream>>>(agg, W1, b1, (unsigned short*)h);

    // GCN layers 2+3 (one gather of h, fused mu/ls GEMM)
    k_gather <<<N_ / 4,   256, 0, stream>>>(row_start, sorted_src, sorted_w, dinv, h, agg);
    k_gemm_z <<<512,      256, 0, stream>>>(agg, Wmu, bmu, Wls, bls, noise, z);

    // Decoder
    k_decode <<<E_ / 16,  256, 0, stream>>>(src, dst, z, out);
}